// Round 10
// baseline (44.316 us; speedup 1.0000x reference)
//
#include <hip/hip_runtime.h>
#include <math.h>
#include <limits.h>

#define NST 16     // stats chunks per row (pass 1 + Z layout; do not change
                   // without changing accept_row's bitwise-fixed sum order)
#define NCS 32     // score chunks per row (pass 2 spatial split only)
#define PLACEHOLDER (-1)

typedef float f32x4 __attribute__((ext_vector_type(4)));

// exp(x - 16), computed as exp2(x*log2e - 16*log2e). No running max needed:
// logits are O(1), so terms are ~1e-7 and the 128K-term sum ~1e-2 -- all
// comfortably inside f32 range. Softmax p = fexp(l) / sum(fexp(l)).
__device__ __forceinline__ float fexp(float x) {
  return exp2f(fmaf(x, 1.44269504088896340736f, -23.0831206542234143f));
}

// (max, index) combine with first-occurrence tie-break (lower index wins).
__device__ __forceinline__ void comb_mx(float& m, int& i, float m2, int i2) {
  if (m2 > m || (m2 == m && i2 < i)) { m = m2; i = i2; }
}

// Accept decision for one row. MUST be bitwise-identical wherever called
// (k_score prologue and k_finalize): linear 16-term Z sum in chunk order,
// fexp, divide, compare. Returns 1 = accept. Also outputs Z.
__device__ __forceinline__ int accept_row(
    const float* __restrict__ logits, const float* __restrict__ draft,
    const int* __restrict__ dids, const float* __restrict__ uniform,
    const float* __restrict__ ps, int row, int V, float& Zout) {
  float Z = 0.f;
#pragma unroll
  for (int c = 0; c < NST; ++c) Z += ps[row * NST + c];
  Zout = Z;
  const int tok = dids[row];
  const float t_at = fexp(logits[(size_t)row * V + tok]) / Z;
  const float d_at = draft[(size_t)row * V + tok];
  const float u = uniform[row];
  return (d_at > 0.f && (t_at / d_at) >= u) ? 1 : 0;
}

// Pass 1: greedy rows -> per-chunk {max, argmax} (no expf);
//         random rows -> per-chunk sum of exp(l - 16) (branchless).
__global__ __launch_bounds__(256) void k_stats(
    const float* __restrict__ logits, const int* __restrict__ topk,
    float* __restrict__ pm, float* __restrict__ ps, int* __restrict__ pidx,
    int S, int V, int chunk_elems) {
  const int row = blockIdx.y;
  const int chunk = blockIdx.x;
  const int tid = threadIdx.x;
  const int b = row / S;
  const int begin = chunk * chunk_elems;
  const int end = min(begin + chunk_elems, V);
  const int n = max(end - begin, 0);
  const int c4 = n >> 2;
  const float* lrow = logits + (size_t)row * V;
  const f32x4* l4 = (const f32x4*)(lrow + begin);
  const int item = row * NST + chunk;

  __shared__ float shf[4];
  __shared__ int shi[4];
  const int lane = tid & 63;
  const int wv = tid >> 6;

  if (topk[b] == 1) {
    // ---- greedy: max + argmax only ----
    float m = -INFINITY; int mi = INT_MAX;
    for (int i = tid; i < c4; i += 256) {
      f32x4 v = l4[i];
      const int gi = begin + (i << 2);
#pragma unroll
      for (int k = 0; k < 4; ++k)
        if (v[k] > m) { m = v[k]; mi = gi + k; }   // strict >: first idx kept
    }
    for (int j = begin + (c4 << 2) + tid; j < end; j += 256) {
      float x = lrow[j];
      if (x > m) { m = x; mi = j; }
    }
    for (int off = 32; off; off >>= 1) {
      float m2 = __shfl_xor(m, off);
      int   i2 = __shfl_xor(mi, off);
      comb_mx(m, mi, m2, i2);
    }
    if (lane == 0) { shf[wv] = m; shi[wv] = mi; }
    __syncthreads();
    if (tid == 0) {
#pragma unroll
      for (int w = 1; w < 4; ++w) comb_mx(m, mi, shf[w], shi[w]);
      pm[item] = m; pidx[item] = mi;
    }
  } else {
    // ---- random: branchless sum of exp(l - 16) ----
    float ssum = 0.f;
    for (int i = tid; i < c4; i += 256) {
      f32x4 v = l4[i];
      ssum += fexp(v[0]); ssum += fexp(v[1]);
      ssum += fexp(v[2]); ssum += fexp(v[3]);
    }
    for (int j = begin + (c4 << 2) + tid; j < end; j += 256)
      ssum += fexp(lrow[j]);
    for (int off = 32; off; off >>= 1)
      ssum += __shfl_xor(ssum, off);
    if (lane == 0) shf[wv] = ssum;
    __syncthreads();
    if (tid == 0)
      ps[item] = shf[0] + shf[1] + shf[2] + shf[3];
  }
}

// Pass 2: recovered-token argmax, ONLY for the first-rejected row of each
// non-greedy b. Grid is (NCS, B): one block per (score-chunk, batch elem);
// the block derives the target row itself in a short L2-resident prologue.
// NO inter-block sync (device-scope atomics/fences measured catastrophic on
// gfx950: R3/R4/R8). Plain cached loads everywhere: all of pass-2's working
// set (179 MB) fits L3, and NT hints hurt latency hiding at ~6 blocks/CU.
__global__ __launch_bounds__(256) void k_score(
    const float* __restrict__ logits, const float* __restrict__ draft,
    const float* __restrict__ invq, const int* __restrict__ topk,
    const int* __restrict__ dids, const float* __restrict__ uniform,
    const float* __restrict__ ps,
    int S, int V, int chunk_elems,
    float* __restrict__ psm, int* __restrict__ psi) {
  const int b = blockIdx.y;
  if (topk[b] == 1) return;
  const int tid = threadIdx.x;
  const int chunk = blockIdx.x;

  // ---- prologue: find first-rejected row of b (none -> exit) ----
  __shared__ float sInvZ;
  __shared__ int sRow;
  if (tid < 64) {
    int a = 1; float Z = 1.f;
    if (tid < S)
      a = accept_row(logits, draft, dids, uniform, ps, b * S + tid, V, Z);
    unsigned long long rej = __ballot(a == 0);
    int first = rej ? (int)__ffsll(rej) - 1 : -1;
    if (tid == 0) sRow = (first >= 0) ? (b * S + first) : -1;
    // lane `first` holds the Z of the first-rejected row
    float Zf = __shfl(Z, first < 0 ? 0 : first);
    if (tid == 0) sInvZ = 1.0f / Zf;
  }
  __syncthreads();
  const int row = sRow;
  if (row < 0) return;
  const float invZ = sInvZ;
  const int item = row * NCS + chunk;

  const int begin = chunk * chunk_elems;
  const int end = min(begin + chunk_elems, V);
  const int n = max(end - begin, 0);
  const int c4 = n >> 2;
  const float* lrow = logits + (size_t)row * V;
  const float* drow = draft + (size_t)row * V;
  const float* qrow = invq + (size_t)b * V;
  const f32x4* l4 = (const f32x4*)(lrow + begin);
  const f32x4* d4 = (const f32x4*)(drow + begin);
  const f32x4* q4 = (const f32x4*)(qrow + begin);

  __shared__ float shf[4];
  __shared__ int shi[4];
  float smx = -INFINITY; int si = INT_MAX;
  for (int i = tid; i < c4; i += 256) {
    f32x4 lv = l4[i];        // L3-resident from pass 1
    f32x4 dv = d4[i];
    f32x4 qv = q4[i];
    const int gi = begin + (i << 2);
#pragma unroll
    for (int k = 0; k < 4; ++k) {
      float p = fexp(lv[k]) * invZ;
      float sc = fmaxf(p - dv[k], 0.f) * qv[k];
      if (sc > smx) { smx = sc; si = gi + k; }
    }
  }
  for (int j = begin + (c4 << 2) + tid; j < end; j += 256) {
    float p = fexp(lrow[j]) * invZ;
    float sc = fmaxf(p - drow[j], 0.f) * qrow[j];
    if (sc > smx) { smx = sc; si = j; }
  }

  const int lane = tid & 63;
  const int wv = tid >> 6;
  for (int off = 32; off; off >>= 1) {
    float m2 = __shfl_xor(smx, off);
    int   i2 = __shfl_xor(si, off);
    comb_mx(smx, si, m2, i2);
  }
  if (lane == 0) { shf[wv] = smx; shi[wv] = si; }
  __syncthreads();
  if (tid == 0) {
#pragma unroll
    for (int w = 1; w < 4; ++w) comb_mx(smx, si, shf[w], shi[w]);
    psm[item] = smx; psi[item] = si;
  }
}

// Finalize: one block (64 threads) per batch element b. Recomputes accept
// bits with code identical to k_score's prologue; reads psm/psi ONLY for
// the first-rejected row (the one k_score populated).
__global__ __launch_bounds__(64) void k_finalize(
    const float* __restrict__ logits, const float* __restrict__ draft,
    const int* __restrict__ dids, const int* __restrict__ bonus,
    const int* __restrict__ topk, const float* __restrict__ uniform,
    const float* __restrict__ pm, const int* __restrict__ pidx,
    const float* __restrict__ ps,
    const float* __restrict__ psm, const int* __restrict__ psi,
    int B, int S, int V, int* __restrict__ out) {
  const int b = blockIdx.x;
  const int lane = threadIdx.x;
  const bool greedy = (topk[b] == 1);

  __shared__ int tam[8];
  __shared__ int sFirst;

  if (greedy) {
    if (lane < S) {
      const int row = b * S + lane;
      float m = -INFINITY; int mi = INT_MAX;
#pragma unroll
      for (int c = 0; c < NST; ++c)
        comb_mx(m, mi, pm[row * NST + c], pidx[row * NST + c]);
      tam[lane] = mi;
    }
  } else {
    int a = 1; float Z;
    if (lane < S)
      a = accept_row(logits, draft, dids, uniform, ps, b * S + lane, V, Z);
    unsigned long long rej = __ballot(a == 0);
    if (lane == 0) sFirst = rej ? (int)__ffsll(rej) - 1 : -1;
  }
  __syncthreads();

  if (lane == 0) {
    int tokv[9];
    bool rejected_before = false, any_rej = false;
    int first = greedy ? -1 : sFirst;
    int rectok = 0;
    if (!greedy && first >= 0) {
      const int row = b * S + first;
      float m = -INFINITY; int mi = INT_MAX;
#pragma unroll
      for (int c = 0; c < NCS; ++c)
        comb_mx(m, mi, psm[row * NCS + c], psi[row * NCS + c]);
      rectok = mi;
    }
    for (int ss = 0; ss < S; ++ss) {
      const int r = b * S + ss;
      const int dtok = dids[r];
      int t; bool rej;
      if (greedy) {
        const int ta = tam[ss];
        rej = (dtok != ta);
        t = ta;
      } else {
        rej = (ss == first);
        t = rej ? rectok : dtok;
      }
      tokv[ss] = rejected_before ? PLACEHOLDER : t;
      any_rej = any_rej || rej;
      rejected_before = rejected_before || rej;
    }
    tokv[S] = any_rej ? PLACEHOLDER : bonus[b];
    int na = 0;
    const int Sp1 = S + 1;
    for (int j = 0; j < Sp1; ++j) na += (tokv[j] != PLACEHOLDER);
    for (int j = 0; j < Sp1; ++j) out[b * Sp1 + j] = tokv[j];
    out[B * Sp1 + b] = Sp1 - na;            // num_rejected_tokens
    out[B * Sp1 + B + b] = tokv[na - 1];    // last_token_ids
  }
}

extern "C" void kernel_launch(void* const* d_in, const int* in_sizes, int n_in,
                              void* d_out, int out_size, void* d_ws, size_t ws_size,
                              hipStream_t stream) {
  const float* logits = (const float*)d_in[0];
  const float* draft  = (const float*)d_in[1];
  const int*   dids   = (const int*)d_in[2];
  const int*   bonus  = (const int*)d_in[3];
  const int*   topk   = (const int*)d_in[4];
  const float* unif   = (const float*)d_in[5];
  const float* invq   = (const float*)d_in[6];
  int* out = (int*)d_out;

  const int B = in_sizes[3];
  const int S = in_sizes[2] / B;
  const int V = in_sizes[0] / in_sizes[2];
  const int nrows = B * S;

  char* w = (char*)d_ws;
  float* pm   = (float*)w; w += (size_t)nrows * NST * sizeof(float);
  float* ps   = (float*)w; w += (size_t)nrows * NST * sizeof(float);
  int*   pidx = (int*)w;   w += (size_t)nrows * NST * sizeof(int);
  float* psm  = (float*)w; w += (size_t)nrows * NCS * sizeof(float);
  int*   psi  = (int*)w;   w += (size_t)nrows * NCS * sizeof(int);

  int ce_stats = (V + NST - 1) / NST;
  ce_stats = (ce_stats + 3) & ~3;     // float4-aligned chunk starts
  int ce_score = (V + NCS - 1) / NCS;
  ce_score = (ce_score + 3) & ~3;

  dim3 grid1(NST, nrows);
  dim3 grid2(NCS, B);
  k_stats<<<grid1, dim3(256), 0, stream>>>(logits, topk, pm, ps, pidx,
                                           S, V, ce_stats);
  k_score<<<grid2, dim3(256), 0, stream>>>(
      logits, draft, invq, topk, dids, unif, ps, S, V, ce_score, psm, psi);
  k_finalize<<<dim3(B), dim3(64), 0, stream>>>(
      logits, draft, dids, bonus, topk, unif, pm, pidx, ps, psm, psi,
      B, S, V, out);
}